// Round 5
// baseline (182.378 us; speedup 1.0000x reference)
//
#include <hip/hip_runtime.h>
#include <hip/hip_bf16.h>

#define NB 16
#define QL 1024
#define DLEN 4096
#define HD 128

typedef __attribute__((ext_vector_type(8))) short short8;
typedef __attribute__((ext_vector_type(4))) float f32x4;

__device__ __forceinline__ short bf16_of(float x) {
  union { __hip_bfloat16 h; short s; } u;
  u.h = __float2bfloat16(x);
  return u.s;
}

__device__ __forceinline__ short8 cvt8(float4 a, float4 b) {
  short8 r;
  r[0] = bf16_of(a.x); r[1] = bf16_of(a.y); r[2] = bf16_of(a.z); r[3] = bf16_of(a.w);
  r[4] = bf16_of(b.x); r[5] = bf16_of(b.y); r[6] = bf16_of(b.z); r[7] = bf16_of(b.w);
  return r;
}

// Pass 1: convert doc (fp32) -> bf16 in d_ws, once.
__global__ __launch_bounds__(256) void cvt_doc(const float* __restrict__ in,
                                               short8* __restrict__ outw) {
  const size_t i = (size_t)blockIdx.x * 256 + threadIdx.x;  // 8 floats/thread
  const float* p = in + i * 8;
  outw[i] = cvt8(*(const float4*)p, *(const float4*)(p + 4));
}

// One pipeline stage: all memory for one 16-k step (5 KB/wave in flight).
struct ItBuf {
  short8 d0, d1, d2, d3;  // doc bf16 fragments (A operands)
  int4 m;                 // doc_mask
  float4 s;               // sim
};

__device__ __forceinline__ ItBuf load_it(const __hip_bfloat16* __restrict__ dbase,
                                         const int* __restrict__ mbase,
                                         const float* __restrict__ sbase, int it) {
  const __hip_bfloat16* dr = dbase + (size_t)(it * 16) * HD;
  ItBuf x;
  x.d0 = *(const short8*)(dr);
  x.d1 = *(const short8*)(dr + 32);
  x.d2 = *(const short8*)(dr + 64);
  x.d3 = *(const short8*)(dr + 96);
  x.m = *(const int4*)(mbase + it * 16);
  x.s = *(const float4*)(sbase + it * 16);
  return x;
}

// Block: 512 threads = 8 waves = 8 k-chunks of 512 for one 16-row q tile.
// Structural double-buffer: step p's data is loaded during step p-1's compute;
// the cross-step dataflow forces the compiler to keep loads live in registers
// (round-4 lesson: VGPR_Count=32 meant serialized loads -> latency-bound).
// MFMA(A=doc, B=Q): lane(grp,li) owns q=qbase+li, k=kb+grp*4+r. No-max softmax
// (scores ~N(0,1); masked -> exp underflows to exact 0) -> l,n k-splittable.
__global__ __launch_bounds__(512, 4) void atten_cross(
    const float* __restrict__ qin, const __hip_bfloat16* __restrict__ dws,
    const int* __restrict__ dmask, const float* __restrict__ sim,
    float* __restrict__ out) {
  const int flat = blockIdx.x;
  const int b = flat & 15;        // flat%8 == b%8 -> one batch's blocks share an XCD
  const int qt = flat >> 4;       // 0..63
  const int tid = threadIdx.x;
  const int wave = tid >> 6;
  const int lane = tid & 63;
  const int grp = lane >> 4;
  const int li = lane & 15;
  const int qbase = qt * 16;
  const int k0 = wave * (DLEN / 8);
  constexpr int NIT = (DLEN / 8) / 16;  // 32 steps of 16 k

  // B fragment (Q): row qbase+li, dims grp*8 + c*32 + [0,8)
  const float* q0 = qin + ((size_t)b * QL + qbase + li) * HD + grp * 8;
  short8 bfrag[4];
#pragma unroll
  for (int c = 0; c < 4; ++c)
    bfrag[c] = cvt8(*(const float4*)(q0 + c * 32), *(const float4*)(q0 + c * 32 + 4));

  const __hip_bfloat16* dbase = dws + ((size_t)b * DLEN + k0 + li) * HD + grp * 8;
  const int* mbase = dmask + (size_t)b * DLEN + k0 + grp * 4;
  const float* sbase = sim + ((size_t)b * QL + qbase + li) * DLEN + k0 + grp * 4;

  float l = 0.f, n = 0.f;
  constexpr float scale = 0.088388347648318447f;  // 1/sqrt(128)

#define CONSUME(X)                                                         \
  {                                                                        \
    f32x4 acc = {0.f, 0.f, 0.f, 0.f};                                      \
    acc = __builtin_amdgcn_mfma_f32_16x16x32_bf16((X).d0, bfrag[0], acc, 0, 0, 0); \
    acc = __builtin_amdgcn_mfma_f32_16x16x32_bf16((X).d1, bfrag[1], acc, 0, 0, 0); \
    acc = __builtin_amdgcn_mfma_f32_16x16x32_bf16((X).d2, bfrag[2], acc, 0, 0, 0); \
    acc = __builtin_amdgcn_mfma_f32_16x16x32_bf16((X).d3, bfrag[3], acc, 0, 0, 0); \
    const int mm[4] = {(X).m.x, (X).m.y, (X).m.z, (X).m.w};                \
    const float ss[4] = {(X).s.x, (X).s.y, (X).s.z, (X).s.w};              \
    _Pragma("unroll") for (int r = 0; r < 4; ++r) {                        \
      float e = __expf(acc[r] * scale);                                    \
      e = mm[r] ? e : 0.f; /* identical to exp(-9999)==0 */                \
      l += e;                                                              \
      n = fmaf(e, ss[r], n);                                               \
    }                                                                      \
  }

  ItBuf A = load_it(dbase, mbase, sbase, 0);
#pragma unroll 1
  for (int p = 0; p < NIT / 2; ++p) {
    ItBuf B = load_it(dbase, mbase, sbase, 2 * p + 1);   // in flight over CONSUME(A)
    CONSUME(A);
    const int nx = (2 * p + 2 < NIT) ? 2 * p + 2 : NIT - 1;  // tail: dead reload
    A = load_it(dbase, mbase, sbase, nx);                // in flight over CONSUME(B)
    CONSUME(B);
  }
#undef CONSUME

  // sum over the 4 groups (k sub-slices); lanes with equal li share q
  l += __shfl_xor(l, 16, 64); l += __shfl_xor(l, 32, 64);
  n += __shfl_xor(n, 16, 64); n += __shfl_xor(n, 32, 64);

  __shared__ float red_l[8][16];
  __shared__ float red_n[8][16];
  if (lane < 16) { red_l[wave][li] = l; red_n[wave][li] = n; }
  __syncthreads();
  if (tid < 16) {
    float lt = 0.f, nt = 0.f;
#pragma unroll
    for (int w = 0; w < 8; ++w) { lt += red_l[w][tid]; nt += red_n[w][tid]; }
    float v = nt / lt;
#pragma unroll
    for (int m = 8; m >= 1; m >>= 1) v += __shfl_xor(v, m, 64);
    if (tid == 0) atomicAdd(out + b, v);
  }
}

extern "C" void kernel_launch(void* const* d_in, const int* in_sizes, int n_in,
                              void* d_out, int out_size, void* d_ws, size_t ws_size,
                              hipStream_t stream) {
  const float* qin = (const float*)d_in[0];
  // d_in[1] = query_mask: unused by the reference
  const float* doc = (const float*)d_in[2];
  const int* dmask = (const int*)d_in[3];
  const float* sim = (const float*)d_in[4];
  float* out = (float*)d_out;

  hipMemsetAsync(out, 0, (size_t)out_size * sizeof(float), stream);

  // doc fp32 -> bf16 into workspace (16.78 MB)
  short8* dws = (short8*)d_ws;
  const size_t doc_elems = (size_t)NB * DLEN * HD;
  cvt_doc<<<doc_elems / (8 * 256), 256, 0, stream>>>(doc, dws);

  dim3 grid(NB * (QL / 16));  // 1024 blocks: flat = qt*16 + b
  atten_cross<<<grid, 512, 0, stream>>>(qin, (const __hip_bfloat16*)d_ws,
                                        dmask, sim, out);
}

// Round 6
// 175.005 us; speedup vs baseline: 1.0421x; 1.0421x over previous
//
#include <hip/hip_runtime.h>
#include <hip/hip_bf16.h>

#define NB 16
#define QL 1024
#define DLEN 4096
#define HD 128

typedef __attribute__((ext_vector_type(8))) short short8;
typedef __attribute__((ext_vector_type(4))) float f32x4;

#define KCHUNK 256
#define NCHUNK (DLEN / KCHUNK)   // 16
#define PSTRIDE (KCHUNK + 1)     // +1 float pad -> ds_write conflicts <= 4-way

__device__ __forceinline__ short bf16_of(float x) {
  union { __hip_bfloat16 h; short s; } u;
  u.h = __float2bfloat16(x);
  return u.s;
}

__device__ __forceinline__ short8 cvt8(float4 a, float4 b) {
  short8 r;
  r[0] = bf16_of(a.x); r[1] = bf16_of(a.y); r[2] = bf16_of(a.z); r[3] = bf16_of(a.w);
  r[4] = bf16_of(b.x); r[5] = bf16_of(b.y); r[6] = bf16_of(b.z); r[7] = bf16_of(b.w);
  return r;
}

// Pass 1: doc fp32 -> bf16 in d_ws, once (removes per-q-tile reconversion).
__global__ __launch_bounds__(256) void cvt_doc(const float* __restrict__ in,
                                               short8* __restrict__ outw) {
  const size_t i = (size_t)blockIdx.x * 256 + threadIdx.x;  // 8 floats/thread
  const float* p = in + i * 8;
  outw[i] = cvt8(*(const float4*)p, *(const float4*)(p + 4));
}

// Round-6 structure: decouple MFMA fragment layout from the sim stream.
// Block = one 16-row q tile, 512 threads = 8 waves. Per 256-k chunk:
//   Phase A: waves compute exp'd P[16q][256k] via MFMA -> LDS (ping-pong),
//            accumulating softmax denominator l. Doc is bf16 (L2-hot).
//   Phase B: COALESCED sim stream - each wave reads whole q-rows as
//            64 lanes x float4 = 1KB/instr, multiplies P from LDS into n.
// Coalescing by construction fixes round 2-5's latency wall (every global
// load was 16B/lane scattered over 16 cachelines; compiler register-minimizing
// killed MLP). No-max softmax: scores ~N(0,1), masked -> exp underflows to
// exact 0 as in ref, so l,n are plain k-splittable sums.
__global__ __launch_bounds__(512, 4) void atten_cross(
    const float* __restrict__ qin, const __hip_bfloat16* __restrict__ dws,
    const int* __restrict__ dmask, const float* __restrict__ sim,
    float* __restrict__ out) {
  const int flat = blockIdx.x;
  const int b = flat & 15;        // flat%8 == b%8 -> one batch's blocks share an XCD
  const int qt = flat >> 4;       // 0..63
  const int tid = threadIdx.x;
  const int w = tid >> 6;         // wave 0..7
  const int lane = tid & 63;
  const int grp = lane >> 4;
  const int li = lane & 15;
  const int qbase = qt * 16;

  __shared__ float Pbuf[2][16][PSTRIDE];
  __shared__ float red_l[8][16];
  __shared__ float red_n[16];

  // B fragment (Q): row qbase+li, dims grp*8 + cc*32 + [0,8)
  const float* q0 = qin + ((size_t)b * QL + qbase + li) * HD + grp * 8;
  short8 bfrag[4];
#pragma unroll
  for (int cc = 0; cc < 4; ++cc)
    bfrag[cc] = cvt8(*(const float4*)(q0 + cc * 32), *(const float4*)(q0 + cc * 32 + 4));

  const __hip_bfloat16* dbase = dws + ((size_t)b * DLEN + li) * HD + grp * 8;
  const int* mbase = dmask + (size_t)b * DLEN + grp * 4;
  const float* srow0 = sim + ((size_t)b * QL + qbase + 2 * w) * DLEN + lane * 4;
  const float* srow1 = srow0 + DLEN;

  float l = 0.f;           // denominator partial for q = li (this wave's k slices)
  float n0 = 0.f, n1 = 0.f;  // numerator partials for q rows 2w, 2w+1
  constexpr float scale = 0.088388347648318447f;  // 1/sqrt(128)

  // Phase A for chunk c into buffer pb: this wave covers k in [c*256+w*32, +32)
#define PHASEA(c, pb)                                                          \
  {                                                                            \
    _Pragma("unroll") for (int t = 0; t < 2; ++t) {                            \
      const int koff = (c) * KCHUNK + w * 32 + t * 16;                         \
      const __hip_bfloat16* dr = dbase + (size_t)koff * HD;                    \
      short8 af[4];                                                            \
      _Pragma("unroll") for (int cc = 0; cc < 4; ++cc)                         \
          af[cc] = *(const short8*)(dr + cc * 32);                             \
      const int4 mk = *(const int4*)(mbase + koff);                            \
      f32x4 acc = {0.f, 0.f, 0.f, 0.f};                                        \
      _Pragma("unroll") for (int cc = 0; cc < 4; ++cc)                         \
          acc = __builtin_amdgcn_mfma_f32_16x16x32_bf16(af[cc], bfrag[cc],     \
                                                        acc, 0, 0, 0);         \
      const int mm[4] = {mk.x, mk.y, mk.z, mk.w};                              \
      float4 ev;                                                               \
      float* evp = &ev.x;                                                      \
      _Pragma("unroll") for (int r = 0; r < 4; ++r) {                          \
        float e = __expf(acc[r] * scale);                                      \
        e = mm[r] ? e : 0.f; /* == exp(-9999) == 0 */                          \
        evp[r] = e;                                                            \
        l += e;                                                                \
      }                                                                        \
      *(float4*)&Pbuf[pb][li][w * 32 + t * 16 + grp * 4] = ev;                 \
    }                                                                          \
  }

  // Phase B for chunk c from buffer pb: wave streams q rows 2w, 2w+1 coalesced
#define PHASEB(c, pb)                                                          \
  {                                                                            \
    const float4 sv0 = *(const float4*)(srow0 + (size_t)(c) * KCHUNK);         \
    const float4 sv1 = *(const float4*)(srow1 + (size_t)(c) * KCHUNK);         \
    const float4 pv0 = *(const float4*)&Pbuf[pb][2 * w][lane * 4];             \
    const float4 pv1 = *(const float4*)&Pbuf[pb][2 * w + 1][lane * 4];         \
    n0 = fmaf(sv0.x, pv0.x, n0); n0 = fmaf(sv0.y, pv0.y, n0);                  \
    n0 = fmaf(sv0.z, pv0.z, n0); n0 = fmaf(sv0.w, pv0.w, n0);                  \
    n1 = fmaf(sv1.x, pv1.x, n1); n1 = fmaf(sv1.y, pv1.y, n1);                  \
    n1 = fmaf(sv1.z, pv1.z, n1); n1 = fmaf(sv1.w, pv1.w, n1);                  \
  }

  PHASEA(0, 0);
  __syncthreads();
#pragma unroll 1
  for (int c = 0; c < NCHUNK; ++c) {
    if (c + 1 < NCHUNK) PHASEA(c + 1, (c + 1) & 1);  // overlaps B(c)'s sim stream
    PHASEB(c, c & 1);
    __syncthreads();
  }
#undef PHASEA
#undef PHASEB

  // l: sum the 4 grp groups -> lane li holds wave-partial for q=li
  l += __shfl_xor(l, 16, 64);
  l += __shfl_xor(l, 32, 64);
  if (lane < 16) red_l[w][li] = l;

  // n: full-wave reduce (each wave owns its two q rows exclusively)
#pragma unroll
  for (int m = 32; m >= 1; m >>= 1) {
    n0 += __shfl_xor(n0, m, 64);
    n1 += __shfl_xor(n1, m, 64);
  }
  if (lane == 0) { red_n[2 * w] = n0; red_n[2 * w + 1] = n1; }
  __syncthreads();

  if (tid < 16) {
    float lt = 0.f;
#pragma unroll
    for (int ww = 0; ww < 8; ++ww) lt += red_l[ww][tid];
    float v = red_n[tid] / lt;
#pragma unroll
    for (int m = 8; m >= 1; m >>= 1) v += __shfl_xor(v, m, 64);
    if (tid == 0) atomicAdd(out + b, v);
  }
}

extern "C" void kernel_launch(void* const* d_in, const int* in_sizes, int n_in,
                              void* d_out, int out_size, void* d_ws, size_t ws_size,
                              hipStream_t stream) {
  const float* qin = (const float*)d_in[0];
  // d_in[1] = query_mask: unused by the reference
  const float* doc = (const float*)d_in[2];
  const int* dmask = (const int*)d_in[3];
  const float* sim = (const float*)d_in[4];
  float* out = (float*)d_out;

  hipMemsetAsync(out, 0, (size_t)out_size * sizeof(float), stream);

  // doc fp32 -> bf16 into workspace (16.78 MB)
  short8* dws = (short8*)d_ws;
  const size_t doc_elems = (size_t)NB * DLEN * HD;
  cvt_doc<<<doc_elems / (8 * 256), 256, 0, stream>>>(doc, dws);

  dim3 grid(NB * (QL / 16));  // 1024 blocks: flat = qt*16 + b
  atten_cross<<<grid, 512, 0, stream>>>(qin, (const __hip_bfloat16*)d_ws,
                                        dmask, sim, out);
}

// Round 7
// 171.290 us; speedup vs baseline: 1.0647x; 1.0217x over previous
//
#include <hip/hip_runtime.h>
#include <hip/hip_bf16.h>

#define NB 16
#define QL 1024
#define DLEN 4096
#define HD 128

typedef __attribute__((ext_vector_type(8))) short short8;
typedef __attribute__((ext_vector_type(4))) float f32x4;

#define KCHUNK 512
#define NCHUNK (DLEN / KCHUNK)   // 8
#define PSTRIDE (KCHUNK + 4)     // float4-aligned pad

__device__ __forceinline__ short bf16_of(float x) {
  union { __hip_bfloat16 h; short s; } u;
  u.h = __float2bfloat16(x);
  return u.s;
}

__device__ __forceinline__ short8 cvt8(float4 a, float4 b) {
  short8 r;
  r[0] = bf16_of(a.x); r[1] = bf16_of(a.y); r[2] = bf16_of(a.z); r[3] = bf16_of(a.w);
  r[4] = bf16_of(b.x); r[5] = bf16_of(b.y); r[6] = bf16_of(b.z); r[7] = bf16_of(b.w);
  return r;
}

// Pass 1: doc fp32 -> bf16 in d_ws, once.
__global__ __launch_bounds__(256) void cvt_doc(const float* __restrict__ in,
                                               short8* __restrict__ outw) {
  const size_t i = (size_t)blockIdx.x * 256 + threadIdx.x;  // 8 floats/thread
  const float* p = in + i * 8;
  outw[i] = cvt8(*(const float4*)p, *(const float4*)(p + 4));
}

// Round 7: R6 structure with DEEP per-interval load sets (the m13-copy shape).
// Rounds 2-6 all plateaued at ~880 GB/s = ~1.3 outstanding loads/CU: each wave
// issued 1-2 loads then waited. Now per barrier interval each wave issues
// 4 independent coalesced sim float4-loads (phase B, 1KB/instr) + 16 doc loads
// of the NEXT chunk (phase A, L2-hot) -- dataflow-independent, so they stay
// in flight together. Barriers: 8/block (KCHUNK=512, fp32 P ping-pong, 66KB
// LDS -> 2 blocks/CU = 16 waves/CU).
// MFMA(A=doc,B=Q): lane(grp,li) holds P[q=qbase+li][k=koff+grp*4+r].
// No-max softmax: scores ~N(0,1); masked -> exp underflows to exact 0 as ref.
__global__ __launch_bounds__(512, 4) void atten_cross(
    const float* __restrict__ qin, const __hip_bfloat16* __restrict__ dws,
    const int* __restrict__ dmask, const float* __restrict__ sim,
    float* __restrict__ out) {
  const int flat = blockIdx.x;
  const int b = flat & 15;        // flat%8 == b%8 -> one batch's blocks share an XCD
  const int qt = flat >> 4;       // 0..63
  const int tid = threadIdx.x;
  const int w = tid >> 6;         // wave 0..7
  const int lane = tid & 63;
  const int grp = lane >> 4;
  const int li = lane & 15;
  const int qbase = qt * 16;

  __shared__ float Pbuf[2][16][PSTRIDE];  // 2*16*516*4 = 66 KB
  __shared__ float red_l[8][16];
  __shared__ float red_n[16];

  // B fragment (Q): row qbase+li, dims grp*8 + cc*32 + [0,8)
  const float* q0 = qin + ((size_t)b * QL + qbase + li) * HD + grp * 8;
  short8 bfrag[4];
#pragma unroll
  for (int cc = 0; cc < 4; ++cc)
    bfrag[cc] = cvt8(*(const float4*)(q0 + cc * 32), *(const float4*)(q0 + cc * 32 + 4));

  const __hip_bfloat16* dbase = dws + ((size_t)b * DLEN + li) * HD + grp * 8;
  const int* mbase = dmask + (size_t)b * DLEN + grp * 4;
  const float* srow0 = sim + ((size_t)b * QL + qbase + 2 * w) * DLEN + lane * 4;
  const float* srow1 = srow0 + DLEN;

  float l = 0.f;             // denominator partial, q = li
  float n0 = 0.f, n1 = 0.f;  // numerator partials, q rows 2w / 2w+1
  constexpr float scale = 0.088388347648318447f;  // 1/sqrt(128)

  // Phase A chunk c -> Pbuf[pb]: wave w covers k in [c*512 + w*64, +64)
#define PHASEA(c, pb)                                                          \
  {                                                                            \
    _Pragma("unroll") for (int t = 0; t < 4; ++t) {                            \
      const int koff = (c) * KCHUNK + w * 64 + t * 16;                         \
      const __hip_bfloat16* dr = dbase + (size_t)koff * HD;                    \
      short8 af[4];                                                            \
      _Pragma("unroll") for (int cc = 0; cc < 4; ++cc)                         \
          af[cc] = *(const short8*)(dr + cc * 32);                             \
      const int4 mk = *(const int4*)(mbase + koff);                            \
      f32x4 acc = {0.f, 0.f, 0.f, 0.f};                                        \
      _Pragma("unroll") for (int cc = 0; cc < 4; ++cc)                         \
          acc = __builtin_amdgcn_mfma_f32_16x16x32_bf16(af[cc], bfrag[cc],     \
                                                        acc, 0, 0, 0);         \
      const int mm[4] = {mk.x, mk.y, mk.z, mk.w};                              \
      float4 ev;                                                               \
      float* evp = &ev.x;                                                      \
      _Pragma("unroll") for (int r = 0; r < 4; ++r) {                          \
        float e = __expf(acc[r] * scale);                                      \
        e = mm[r] ? e : 0.f; /* == exp(-9999) == 0 */                          \
        evp[r] = e;                                                            \
        l += e;                                                                \
      }                                                                        \
      *(float4*)&Pbuf[pb][li][w * 64 + t * 16 + grp * 4] = ev;                 \
    }                                                                          \
  }

  // Phase B chunk c from Pbuf[pb]: wave streams q rows 2w, 2w+1 coalesced;
  // 4 independent 1KB loads per wave per interval (linear b128 LDS reads).
#define PHASEB(c, pb)                                                          \
  {                                                                            \
    _Pragma("unroll") for (int i = 0; i < 2; ++i) {                            \
      const float4 sv0 = *(const float4*)(srow0 + (size_t)(c) * KCHUNK + i * 256); \
      const float4 sv1 = *(const float4*)(srow1 + (size_t)(c) * KCHUNK + i * 256); \
      const float4 pv0 = *(const float4*)&Pbuf[pb][2 * w][i * 256 + lane * 4]; \
      const float4 pv1 = *(const float4*)&Pbuf[pb][2 * w + 1][i * 256 + lane * 4]; \
      n0 = fmaf(sv0.x, pv0.x, n0); n0 = fmaf(sv0.y, pv0.y, n0);                \
      n0 = fmaf(sv0.z, pv0.z, n0); n0 = fmaf(sv0.w, pv0.w, n0);                \
      n1 = fmaf(sv1.x, pv1.x, n1); n1 = fmaf(sv1.y, pv1.y, n1);                \
      n1 = fmaf(sv1.z, pv1.z, n1); n1 = fmaf(sv1.w, pv1.w, n1);                \
    }                                                                          \
  }

  PHASEA(0, 0);
  __syncthreads();
#pragma unroll 1
  for (int c = 0; c < NCHUNK; ++c) {
    if (c + 1 < NCHUNK) PHASEA(c + 1, (c + 1) & 1);  // next-chunk producer
    PHASEB(c, c & 1);                                // current-chunk sim stream
    __syncthreads();
  }
#undef PHASEA
#undef PHASEB

  // l: sum over the 4 grp groups; lanes sharing li share q
  l += __shfl_xor(l, 16, 64);
  l += __shfl_xor(l, 32, 64);
  if (lane < 16) red_l[w][li] = l;

  // n: full-wave reduce (wave owns its two q rows exclusively)
#pragma unroll
  for (int m = 32; m >= 1; m >>= 1) {
    n0 += __shfl_xor(n0, m, 64);
    n1 += __shfl_xor(n1, m, 64);
  }
  if (lane == 0) { red_n[2 * w] = n0; red_n[2 * w + 1] = n1; }
  __syncthreads();

  if (tid < 16) {
    float lt = 0.f;
#pragma unroll
    for (int ww = 0; ww < 8; ++ww) lt += red_l[ww][tid];
    float v = red_n[tid] / lt;
#pragma unroll
    for (int m = 8; m >= 1; m >>= 1) v += __shfl_xor(v, m, 64);
    if (tid == 0) atomicAdd(out + b, v);
  }
}

extern "C" void kernel_launch(void* const* d_in, const int* in_sizes, int n_in,
                              void* d_out, int out_size, void* d_ws, size_t ws_size,
                              hipStream_t stream) {
  const float* qin = (const float*)d_in[0];
  // d_in[1] = query_mask: unused by the reference
  const float* doc = (const float*)d_in[2];
  const int* dmask = (const int*)d_in[3];
  const float* sim = (const float*)d_in[4];
  float* out = (float*)d_out;

  hipMemsetAsync(out, 0, (size_t)out_size * sizeof(float), stream);

  // doc fp32 -> bf16 into workspace (16.78 MB)
  short8* dws = (short8*)d_ws;
  const size_t doc_elems = (size_t)NB * DLEN * HD;
  cvt_doc<<<doc_elems / (8 * 256), 256, 0, stream>>>(doc, dws);

  dim3 grid(NB * (QL / 16));  // 1024 blocks: flat = qt*16 + b
  atten_cross<<<grid, 512, 0, stream>>>(qin, (const __hip_bfloat16*)d_ws,
                                        dmask, sim, out);
}